// Round 8
// baseline (77.937 us; speedup 1.0000x reference)
//
#include <hip/hip_runtime.h>

#define NG 2
#define NV 320
#define GV 640      // NG*NV
#define DHALF 128   // CODE_DIM/NG
#define BSROWS 2048 // B*S
#define NROWS 4096  // BSROWS*NG
#define K_DIM 512
#define NPART 256   // row-kernel blocks (partials)
#define LDA 40      // f16 per LDS row (32 + 8 pad); 80 B, 16B-aligned

typedef _Float16 half8 __attribute__((ext_vector_type(8)));
typedef float floatx4 __attribute__((ext_vector_type(4)));

#define MFMA16(a, b, c) __builtin_amdgcn_mfma_f32_16x16x32_f16(a, b, c, 0, 0, 0)

// ---------------- GEMM: logits = x@W + b; BM=64 BN=32 BK=32; in-loop hi/lo split -----------
// A: X f32 -> (x*64) f16 hi/lo split in-loop (R6-validated, bit-identical).
// B: W f32 [k][n] -> (w*1024) f16 hi/lo, transposed into LDS [n][k] in-loop (same formula
//    as the prep kernel -> bit-identical logits).
__global__ __launch_bounds__(256) void gemm_fused_kernel(
    const float* __restrict__ X, const float* __restrict__ W,
    const float* __restrict__ bias, float* __restrict__ C,
    int* __restrict__ counter) {
  __shared__ _Float16 Ah[2][64 * LDA], Al[2][64 * LDA];
  __shared__ _Float16 Bh[2][32 * LDA], Bl[2][32 * LDA];
  const int tid = threadIdx.x;
  if (blockIdx.x == 0 && blockIdx.y == 0 && tid == 0) *counter = 0;
  const int bm = blockIdx.y * 64, bn = blockIdx.x * 32;
  const int w = tid >> 6, lane = tid & 63;
  const int wr = w >> 1, wc = w & 1;

  // A staging: row = tid>>2 (0..63), k-chunk = (tid&3)*8
  const int srow = tid >> 2;
  const int skc = (tid & 3) << 3;
  const float* Xg = X + (bm + srow) * K_DIM + skc;
  const int sA = srow * LDA + skc;
  // B staging: k-row = tid>>3 (0..31), n-chunk = (tid&7)*4
  const int bkr = tid >> 3;
  const int bnc = (tid & 7) << 2;
  const float* Wgp = W + bkr * GV + bn + bnc;

  const int frow = lane & 15;
  const int fkg = (lane >> 4) << 3;
  const int a0o = (wr * 32 + frow) * LDA + fkg;
  const int b0o = (wc * 16 + frow) * LDA + fkg;

  floatx4 acc[2] = {};

  // ---- helpers as lambdas (compile-time inlined) ----
  auto splitA = [&](float4 xa, float4 xb, half8& hv, half8& lv) {
    float xv[8] = {xa.x, xa.y, xa.z, xa.w, xb.x, xb.y, xb.z, xb.w};
#pragma unroll
    for (int j = 0; j < 8; ++j) {
      float s = xv[j] * 64.0f;
      _Float16 h = (_Float16)s;
      hv[j] = h;
      lv[j] = (_Float16)(s - (float)h);
    }
  };

  // prologue: stage tile 0 into buffer 0
  {
    float4 xa = *(const float4*)(Xg);
    float4 xb = *(const float4*)(Xg + 4);
    float4 wv = *(const float4*)(Wgp);
    half8 hv, lv;
    splitA(xa, xb, hv, lv);
    *(half8*)&Ah[0][sA] = hv;
    *(half8*)&Al[0][sA] = lv;
    float wf[4] = {wv.x, wv.y, wv.z, wv.w};
#pragma unroll
    for (int j = 0; j < 4; ++j) {
      float s = wf[j] * 1024.0f;
      _Float16 h = (_Float16)s;
      Bh[0][(bnc + j) * LDA + bkr] = h;
      Bl[0][(bnc + j) * LDA + bkr] = (_Float16)(s - (float)h);
    }
  }
  __syncthreads();

#pragma unroll 2
  for (int k0 = 0; k0 < K_DIM; k0 += 32) {
    const int cur = (k0 >> 5) & 1;
    const int nxt = cur ^ 1;
    const bool more = (k0 + 32) < K_DIM;

    // issue next tile's global loads early (hide under MFMAs)
    float4 xa, xb, wv;
    if (more) {
      xa = *(const float4*)(Xg + k0 + 32);
      xb = *(const float4*)(Xg + k0 + 36);
      wv = *(const float4*)(Wgp + (k0 + 32) * GV);
    }

    half8 ah0 = *(const half8*)&Ah[cur][a0o];
    half8 ah1 = *(const half8*)&Ah[cur][a0o + 16 * LDA];
    half8 al0 = *(const half8*)&Al[cur][a0o];
    half8 al1 = *(const half8*)&Al[cur][a0o + 16 * LDA];
    half8 bh0 = *(const half8*)&Bh[cur][b0o];
    half8 bl0 = *(const half8*)&Bl[cur][b0o];

    // per-output order: hh, hl, lh (bit-identical to prior rounds)
    acc[0] = MFMA16(ah0, bh0, acc[0]);
    acc[1] = MFMA16(ah1, bh0, acc[1]);
    acc[0] = MFMA16(ah0, bl0, acc[0]);
    acc[1] = MFMA16(ah1, bl0, acc[1]);
    acc[0] = MFMA16(al0, bh0, acc[0]);
    acc[1] = MFMA16(al1, bh0, acc[1]);

    if (more) {
      half8 hv, lv;
      splitA(xa, xb, hv, lv);
      *(half8*)&Ah[nxt][sA] = hv;
      *(half8*)&Al[nxt][sA] = lv;
      float wf[4] = {wv.x, wv.y, wv.z, wv.w};
#pragma unroll
      for (int j = 0; j < 4; ++j) {
        float s = wf[j] * 1024.0f;
        _Float16 h = (_Float16)s;
        Bh[nxt][(bnc + j) * LDA + bkr] = h;
        Bl[nxt][(bnc + j) * LDA + bkr] = (_Float16)(s - (float)h);
      }
    }
    __syncthreads();
  }

  // C/D: col = lane&15, row = (lane>>4)*4 + reg
  const float inv = 1.0f / 65536.0f;
  const int col = bn + wc * 16 + (lane & 15);
  const float bb = bias[col];
#pragma unroll
  for (int i = 0; i < 2; ++i) {
    const int r0 = bm + wr * 32 + i * 16 + ((lane >> 4) << 2);
#pragma unroll
    for (int q = 0; q < 4; ++q)
      C[(r0 + q) * GV + col] = acc[i][q] * inv + bb;
  }
}

// ---------------- Row kernel: 4 rows/wave; fused gather; partials; last-block tail ---------
__global__ __launch_bounds__(256) void row_fused_kernel(
    const float* __restrict__ logits, const float* __restrict__ gumbels,
    const float* __restrict__ cvs, float* __restrict__ out,
    float* __restrict__ part, int* __restrict__ counter,
    float* __restrict__ perpOut) {
  __shared__ float accW[4][2][NV];
  __shared__ int lastFlag;
  const int tid = threadIdx.x;
  const int lane = tid & 63;
  const int w = tid >> 6;
  const int rbase = blockIdx.x * 16 + w * 4;  // even

  float p0[5] = {}, p1[5] = {};

#pragma unroll
  for (int i = 0; i < 4; ++i) {
    const int r = rbase + i;
    const int bs = r >> 1, g = i & 1;  // g == r&1 since rbase is even
    const float* lrow = logits + bs * GV + g * NV;
    const float* grow = gumbels + r * NV;
    float lv[5], av[5];
#pragma unroll
    for (int j = 0; j < 5; ++j) {
      lv[j] = lrow[lane + 64 * j];
      av[j] = lv[j] + grow[lane + 64 * j];
    }
    float m = lv[0];
#pragma unroll
    for (int j = 1; j < 5; ++j) m = fmaxf(m, lv[j]);
#pragma unroll
    for (int o = 32; o > 0; o >>= 1) m = fmaxf(m, __shfl_xor(m, o));
    float e[5];
    float s = 0.f;
#pragma unroll
    for (int j = 0; j < 5; ++j) {
      e[j] = expf(lv[j] - m);
      s += e[j];
    }
#pragma unroll
    for (int o = 32; o > 0; o >>= 1) s += __shfl_xor(s, o);
    const float inv = 1.f / s;
#pragma unroll
    for (int j = 0; j < 5; ++j) {
      if ((i & 1) == 0) p0[j] += e[j] * inv;
      else              p1[j] += e[j] * inv;
    }
    float bv = av[0];
    int bi = lane;
#pragma unroll
    for (int j = 1; j < 5; ++j) {
      if (av[j] > bv) { bv = av[j]; bi = lane + 64 * j; }
    }
#pragma unroll
    for (int o = 32; o > 0; o >>= 1) {
      float ov = __shfl_xor(bv, o);
      int oi = __shfl_xor(bi, o);
      if (ov > bv || (ov == bv && oi < bi)) { bv = ov; bi = oi; }
    }
    const float2 cv = *(const float2*)(cvs + (g * NV + bi) * DHALF + lane * 2);
    *(float2*)(out + bs * 256 + g * DHALF + lane * 2) = cv;
  }

#pragma unroll
  for (int j = 0; j < 5; ++j) {
    accW[w][0][lane + 64 * j] = p0[j];
    accW[w][1][lane + 64 * j] = p1[j];
  }
  __syncthreads();
  for (int i = tid; i < GV; i += 256) {
    const int g = (i < NV) ? 0 : 1;
    const int c = (i < NV) ? i : i - NV;
    part[blockIdx.x * GV + i] =
        (accW[0][g][c] + accW[1][g][c]) + (accW[2][g][c] + accW[3][g][c]);
  }
  __threadfence();
  __syncthreads();
  if (tid == 0) {
    const int old = atomicAdd(counter, 1);
    lastFlag = (old == NPART - 1) ? 1 : 0;
  }
  __syncthreads();

  // last-finishing block reduces all partials (fixed order -> deterministic) + perp
  if (lastFlag) {
    __threadfence();
    float h0 = 0.f, h1 = 0.f;
    for (int col = tid; col < GV; col += 256) {
      float s0 = 0.f, s1 = 0.f, s2 = 0.f, s3 = 0.f;
      for (int b = 0; b < NPART; b += 4) {
        s0 += part[(b + 0) * GV + col];
        s1 += part[(b + 1) * GV + col];
        s2 += part[(b + 2) * GV + col];
        s3 += part[(b + 3) * GV + col];
      }
      const float cs = (s0 + s1) + (s2 + s3);
      const float mm = cs * (1.0f / BSROWS);
      const float t = mm * logf(mm + 1e-7f);
      if (col < NV) h0 += t; else h1 += t;
    }
    __shared__ float r0[256], r1[256];
    r0[tid] = h0;
    r1[tid] = h1;
    __syncthreads();
    for (int s = 128; s > 0; s >>= 1) {
      if (tid < s) { r0[tid] += r0[tid + s]; r1[tid] += r1[tid + s]; }
      __syncthreads();
    }
    if (tid == 0) perpOut[0] = expf(-r0[0]) + expf(-r1[0]);
  }
}

extern "C" void kernel_launch(void* const* d_in, const int* in_sizes, int n_in,
                              void* d_out, int out_size, void* d_ws, size_t ws_size,
                              hipStream_t stream) {
  const float* x = (const float*)d_in[0];
  const float* W = (const float*)d_in[1];
  const float* b = (const float*)d_in[2];
  const float* cvs = (const float*)d_in[3];
  const float* gum = (const float*)d_in[4];
  float* out = (float*)d_out;

  float* logits = (float*)d_ws;                     // 2048*640 f32
  float* part = logits + BSROWS * GV;               // 256*640 f32
  int* counter = (int*)(part + NPART * GV);         // 1 i32 (+pad)

  dim3 ggrid(GV / 32, BSROWS / 64);  // (20, 32) = 640 blocks
  gemm_fused_kernel<<<ggrid, 256, 0, stream>>>(x, W, b, logits, counter);
  row_fused_kernel<<<NPART, 256, 0, stream>>>(logits, gum, cvs, out, part, counter,
                                              out + BSROWS * 256);
}

// Round 9
// 50.271 us; speedup vs baseline: 1.5503x; 1.5503x over previous
//
#include <hip/hip_runtime.h>

#define NG 2
#define NV 320
#define GV 640      // NG*NV
#define DHALF 128   // CODE_DIM/NG
#define BSROWS 2048 // B*S
#define NROWS 4096  // BSROWS*NG
#define K_DIM 512
#define NPART 1024  // row-kernel blocks (partials)
#define NRED 40     // reduce blocks (16 cols each)
#define LDA 40      // f16 per LDS row (32 + 8 pad); 80 B, 16B-aligned

typedef _Float16 half8 __attribute__((ext_vector_type(8)));
typedef float floatx4 __attribute__((ext_vector_type(4)));

#define MFMA16(a, b, c) __builtin_amdgcn_mfma_f32_16x16x32_f16(a, b, c, 0, 0, 0)

// ---------------- GEMM: logits = x@W + b; BM=64 BN=32 BK=32; in-loop hi/lo split -----------
// (R8-validated, ~8 us). A: x*64 -> f16 hi/lo. B: W[k][n]*1024 -> f16 hi/lo transposed to LDS.
__global__ __launch_bounds__(256) void gemm_fused_kernel(
    const float* __restrict__ X, const float* __restrict__ W,
    const float* __restrict__ bias, float* __restrict__ C,
    int* __restrict__ counter) {
  __shared__ _Float16 Ah[2][64 * LDA], Al[2][64 * LDA];
  __shared__ _Float16 Bh[2][32 * LDA], Bl[2][32 * LDA];
  const int tid = threadIdx.x;
  if (blockIdx.x == 0 && blockIdx.y == 0 && tid == 0) *counter = 0;
  const int bm = blockIdx.y * 64, bn = blockIdx.x * 32;
  const int w = tid >> 6, lane = tid & 63;
  const int wr = w >> 1, wc = w & 1;

  const int srow = tid >> 2;
  const int skc = (tid & 3) << 3;
  const float* Xg = X + (bm + srow) * K_DIM + skc;
  const int sA = srow * LDA + skc;
  const int bkr = tid >> 3;
  const int bnc = (tid & 7) << 2;
  const float* Wgp = W + bkr * GV + bn + bnc;

  const int frow = lane & 15;
  const int fkg = (lane >> 4) << 3;
  const int a0o = (wr * 32 + frow) * LDA + fkg;
  const int b0o = (wc * 16 + frow) * LDA + fkg;

  floatx4 acc[2] = {};

  auto splitA = [&](float4 xa, float4 xb, half8& hv, half8& lv) {
    float xv[8] = {xa.x, xa.y, xa.z, xa.w, xb.x, xb.y, xb.z, xb.w};
#pragma unroll
    for (int j = 0; j < 8; ++j) {
      float s = xv[j] * 64.0f;
      _Float16 h = (_Float16)s;
      hv[j] = h;
      lv[j] = (_Float16)(s - (float)h);
    }
  };

  {
    float4 xa = *(const float4*)(Xg);
    float4 xb = *(const float4*)(Xg + 4);
    float4 wv = *(const float4*)(Wgp);
    half8 hv, lv;
    splitA(xa, xb, hv, lv);
    *(half8*)&Ah[0][sA] = hv;
    *(half8*)&Al[0][sA] = lv;
    float wf[4] = {wv.x, wv.y, wv.z, wv.w};
#pragma unroll
    for (int j = 0; j < 4; ++j) {
      float s = wf[j] * 1024.0f;
      _Float16 h = (_Float16)s;
      Bh[0][(bnc + j) * LDA + bkr] = h;
      Bl[0][(bnc + j) * LDA + bkr] = (_Float16)(s - (float)h);
    }
  }
  __syncthreads();

#pragma unroll 2
  for (int k0 = 0; k0 < K_DIM; k0 += 32) {
    const int cur = (k0 >> 5) & 1;
    const int nxt = cur ^ 1;
    const bool more = (k0 + 32) < K_DIM;

    float4 xa, xb, wv;
    if (more) {
      xa = *(const float4*)(Xg + k0 + 32);
      xb = *(const float4*)(Xg + k0 + 36);
      wv = *(const float4*)(Wgp + (k0 + 32) * GV);
    }

    half8 ah0 = *(const half8*)&Ah[cur][a0o];
    half8 ah1 = *(const half8*)&Ah[cur][a0o + 16 * LDA];
    half8 al0 = *(const half8*)&Al[cur][a0o];
    half8 al1 = *(const half8*)&Al[cur][a0o + 16 * LDA];
    half8 bh0 = *(const half8*)&Bh[cur][b0o];
    half8 bl0 = *(const half8*)&Bl[cur][b0o];

    acc[0] = MFMA16(ah0, bh0, acc[0]);
    acc[1] = MFMA16(ah1, bh0, acc[1]);
    acc[0] = MFMA16(ah0, bl0, acc[0]);
    acc[1] = MFMA16(ah1, bl0, acc[1]);
    acc[0] = MFMA16(al0, bh0, acc[0]);
    acc[1] = MFMA16(al1, bh0, acc[1]);

    if (more) {
      half8 hv, lv;
      splitA(xa, xb, hv, lv);
      *(half8*)&Ah[nxt][sA] = hv;
      *(half8*)&Al[nxt][sA] = lv;
      float wf[4] = {wv.x, wv.y, wv.z, wv.w};
#pragma unroll
      for (int j = 0; j < 4; ++j) {
        float s = wf[j] * 1024.0f;
        _Float16 h = (_Float16)s;
        Bh[nxt][(bnc + j) * LDA + bkr] = h;
        Bl[nxt][(bnc + j) * LDA + bkr] = (_Float16)(s - (float)h);
      }
    }
    __syncthreads();
  }

  const float inv = 1.0f / 65536.0f;
  const int col = bn + wc * 16 + (lane & 15);
  const float bb = bias[col];
#pragma unroll
  for (int i = 0; i < 2; ++i) {
    const int r0 = bm + wr * 32 + i * 16 + ((lane >> 4) << 2);
#pragma unroll
    for (int q = 0; q < 4; ++q)
      C[(r0 + q) * GV + col] = acc[i][q] * inv + bb;
  }
}

// ---------------- Row kernel: 1 row/wave; fused gather; per-block partials (R3/R6) ---------
__global__ __launch_bounds__(256) void row_kernel(
    const float* __restrict__ logits, const float* __restrict__ gumbels,
    const float* __restrict__ cvs, float* __restrict__ out,
    float* __restrict__ part) {
  __shared__ float accW[4][NV];
  const int tid = threadIdx.x;
  const int lane = tid & 63;
  const int w = tid >> 6;
  const int r = blockIdx.x * 4 + w;  // row in [0,4096)
  const int bs = r >> 1, g = r & 1;
  const float* lrow = logits + bs * GV + g * NV;
  const float* grow = gumbels + r * NV;

  float lv[5], av[5];
#pragma unroll
  for (int j = 0; j < 5; ++j) {
    lv[j] = lrow[lane + 64 * j];
    av[j] = lv[j] + grow[lane + 64 * j];
  }
  float m = lv[0];
#pragma unroll
  for (int j = 1; j < 5; ++j) m = fmaxf(m, lv[j]);
#pragma unroll
  for (int o = 32; o > 0; o >>= 1) m = fmaxf(m, __shfl_xor(m, o));
  float e[5];
  float s = 0.f;
#pragma unroll
  for (int j = 0; j < 5; ++j) {
    e[j] = expf(lv[j] - m);
    s += e[j];
  }
#pragma unroll
  for (int o = 32; o > 0; o >>= 1) s += __shfl_xor(s, o);
  const float inv = 1.f / s;
#pragma unroll
  for (int j = 0; j < 5; ++j) accW[w][lane + 64 * j] = e[j] * inv;

  float bv = av[0];
  int bi = lane;
#pragma unroll
  for (int j = 1; j < 5; ++j) {
    if (av[j] > bv) { bv = av[j]; bi = lane + 64 * j; }
  }
#pragma unroll
  for (int o = 32; o > 0; o >>= 1) {
    float ov = __shfl_xor(bv, o);
    int oi = __shfl_xor(bi, o);
    if (ov > bv || (ov == bv && oi < bi)) { bv = ov; bi = oi; }
  }

  const float2 cv = *(const float2*)(cvs + (g * NV + bi) * DHALF + lane * 2);
  *(float2*)(out + bs * 256 + g * DHALF + lane * 2) = cv;

  __syncthreads();
  for (int i = tid; i < GV; i += 256) {
    float v = (i < NV) ? (accW[0][i] + accW[2][i]) : (accW[1][i - NV] + accW[3][i - NV]);
    part[blockIdx.x * GV + i] = v;
  }
}

// ---------------- Reduce partials + perplexity: 40 blocks x 16 cols (R7-validated) ---------
__global__ __launch_bounds__(256) void reduce_perp_kernel(
    const float* __restrict__ part, float* __restrict__ hpart,
    int* __restrict__ counter, float* __restrict__ perpOut) {
  const int t = threadIdx.x;
  const int rg = t >> 4;        // 0..15 row-group
  const int co = t & 15;        // 0..15 col offset
  const int col = blockIdx.x * 16 + co;
  float s = 0.f;
  for (int b = rg; b < NPART; b += 16) s += part[b * GV + col];
  __shared__ float red[16][16];
  red[rg][co] = s;
  __syncthreads();
  if (t < 16) {
    float cs = 0.f;
#pragma unroll
    for (int j = 0; j < 16; ++j) cs += red[j][t];
    const float mm = cs * (1.0f / BSROWS);
    float h = mm * logf(mm + 1e-7f);
#pragma unroll
    for (int o = 8; o > 0; o >>= 1) h += __shfl_xor(h, o, 16);
    if (t == 0) {
      hpart[blockIdx.x] = h;
      __threadfence();
      const int old = atomicAdd(counter, 1);
      if (old == NRED - 1) {
        __threadfence();
        float h0 = 0.f, h1 = 0.f;
#pragma unroll
        for (int i = 0; i < 20; ++i) h0 += hpart[i];
#pragma unroll
        for (int i = 20; i < 40; ++i) h1 += hpart[i];
        perpOut[0] = expf(-h0) + expf(-h1);
      }
    }
  }
}

extern "C" void kernel_launch(void* const* d_in, const int* in_sizes, int n_in,
                              void* d_out, int out_size, void* d_ws, size_t ws_size,
                              hipStream_t stream) {
  const float* x = (const float*)d_in[0];
  const float* W = (const float*)d_in[1];
  const float* b = (const float*)d_in[2];
  const float* cvs = (const float*)d_in[3];
  const float* gum = (const float*)d_in[4];
  float* out = (float*)d_out;

  float* logits = (float*)d_ws;                     // 2048*640 f32
  float* part = logits + BSROWS * GV;               // 1024*640 f32
  float* hpart = part + NPART * GV;                 // 40 f32 (+pad)
  int* counter = (int*)(hpart + 64);                // 1 i32

  dim3 ggrid(GV / 32, BSROWS / 64);  // (20, 32) = 640 blocks
  gemm_fused_kernel<<<ggrid, 256, 0, stream>>>(x, W, b, logits, counter);
  row_kernel<<<NROWS / 4, 256, 0, stream>>>(logits, gum, cvs, out, part);
  reduce_perp_kernel<<<NRED, 256, 0, stream>>>(part, hpart, counter, out + BSROWS * 256);
}

// Round 10
// 38.091 us; speedup vs baseline: 2.0461x; 1.3198x over previous
//
#include <hip/hip_runtime.h>

#define NV 320
#define GV 640
#define DHALF 128
#define BSROWS 2048
#define K_DIM 512
#define LDA 40      // f16 per LDS row (32 + 8 pad)
#define NRED 40

typedef _Float16 half8 __attribute__((ext_vector_type(8)));
typedef _Float16 half4 __attribute__((ext_vector_type(4)));
typedef float floatx4 __attribute__((ext_vector_type(4)));

#define MFMA16(a, b, c) __builtin_amdgcn_mfma_f32_16x16x32_f16(a, b, c, 0, 0, 0)

// ---------------- Fused GEMM + row phase -----------------------------------------------
// grid = 128: bid = mtile*2 + g is wrong order; use g = bid&1, mtile = bid>>1.
// Block: rows bm..bm+31, group g (320 cols). 4 waves x 80 cols.
// A: X*64 -> f16 hi/lo via double-buffered LDS (R6/R8-validated staging).
// B: W*1024 -> f16 hi/lo split in-register from direct global fragment loads.
// Epilogue: softmax (raw logits), argmax(l+gumbel), gather, marginal partials.
__global__ __launch_bounds__(256) void gemm_row_kernel(
    const float* __restrict__ X, const float* __restrict__ W,
    const float* __restrict__ bias, const float* __restrict__ gum,
    const float* __restrict__ cvs, float* __restrict__ out,
    float* __restrict__ part, int* __restrict__ counter) {
  __shared__ _Float16 Ah[2][32 * LDA], Al[2][32 * LDA];
  __shared__ float sm_m[4][32], sm_av[4][32], sm_s[4][32];
  __shared__ int sm_ai[4][32], sm_idx[32];

  const int tid = threadIdx.x;
  const int bid = blockIdx.x;
  if (bid == 0 && tid == 0) *counter = 0;
  const int g = bid & 1;
  const int mtile = bid >> 1;
  const int bm = mtile * 32;
  const int w = tid >> 6, lane = tid & 63;
  const int wcol0 = w * 80;
  const int gn0 = g * NV;

  // A staging: srow = tid>>3 (0..31), skc = (tid&7)*4
  const int srow = tid >> 3, skc = (tid & 7) << 2;
  const float* Xg = X + (bm + srow) * K_DIM + skc;
  const int sA = srow * LDA + skc;

  const int frow = lane & 15;        // col-in-tile (B) / row-in-tile (A)
  const int rq0 = (lane >> 4) << 2;  // C/D row base
  const int fkg = (lane >> 4) << 3;  // k offset of fragment
  const float* Wf = W + gn0 + wcol0 + frow;

  floatx4 acc[2][5] = {};

  auto splitA4 = [&](float4 xa, half4& hv, half4& lv) {
    float xv[4] = {xa.x, xa.y, xa.z, xa.w};
#pragma unroll
    for (int j = 0; j < 4; ++j) {
      float s = xv[j] * 64.0f;
      _Float16 h = (_Float16)s;
      hv[j] = h;
      lv[j] = (_Float16)(s - (float)h);
    }
  };

  {  // prologue: A tile 0 -> buf 0
    float4 xa = *(const float4*)(Xg);
    half4 hv, lv;
    splitA4(xa, hv, lv);
    *(half4*)&Ah[0][sA] = hv;
    *(half4*)&Al[0][sA] = lv;
  }
  __syncthreads();

  for (int k0 = 0; k0 < K_DIM; k0 += 32) {
    const int cur = (k0 >> 5) & 1;
    const int nxt = cur ^ 1;
    const bool more = (k0 + 32) < K_DIM;

    float4 xa;
    if (more) xa = *(const float4*)(Xg + k0 + 32);

    // B fragment loads: global -> reg (coalesced across 16-lane col group)
    float wv[5][8];
#pragma unroll
    for (int j = 0; j < 5; ++j)
#pragma unroll
      for (int kk = 0; kk < 8; ++kk)
        wv[j][kk] = Wf[(k0 + fkg + kk) * GV + j * 16];

    half8 ah0 = *(const half8*)&Ah[cur][frow * LDA + fkg];
    half8 ah1 = *(const half8*)&Ah[cur][(16 + frow) * LDA + fkg];
    half8 al0 = *(const half8*)&Al[cur][frow * LDA + fkg];
    half8 al1 = *(const half8*)&Al[cur][(16 + frow) * LDA + fkg];

#pragma unroll
    for (int j = 0; j < 5; ++j) {
      half8 bh, bl;
#pragma unroll
      for (int kk = 0; kk < 8; ++kk) {
        float s = wv[j][kk] * 1024.0f;
        _Float16 h = (_Float16)s;
        bh[kk] = h;
        bl[kk] = (_Float16)(s - (float)h);
      }
      // per-output order hh, hl, lh (bit-identical to validated rounds)
      acc[0][j] = MFMA16(ah0, bh, acc[0][j]);
      acc[0][j] = MFMA16(ah0, bl, acc[0][j]);
      acc[0][j] = MFMA16(al0, bh, acc[0][j]);
      acc[1][j] = MFMA16(ah1, bh, acc[1][j]);
      acc[1][j] = MFMA16(ah1, bl, acc[1][j]);
      acc[1][j] = MFMA16(al1, bh, acc[1][j]);
    }

    if (more) {
      half4 hv, lv;
      splitA4(xa, hv, lv);
      *(half4*)&Ah[nxt][sA] = hv;
      *(half4*)&Al[nxt][sA] = lv;
    }
    __syncthreads();
  }

  // ---------------- epilogue ----------------
  const float inv = 1.0f / 65536.0f;
  float bb[5];
#pragma unroll
  for (int j = 0; j < 5; ++j) bb[j] = bias[gn0 + wcol0 + j * 16 + frow];
#pragma unroll
  for (int i = 0; i < 2; ++i)
#pragma unroll
    for (int j = 0; j < 5; ++j)
#pragma unroll
      for (int q = 0; q < 4; ++q)
        acc[i][j][q] = acc[i][j][q] * inv + bb[j];

  // gumbels for this lane's 8 rows x 5 cols
  float gv[2][5][4];
#pragma unroll
  for (int i = 0; i < 2; ++i)
#pragma unroll
    for (int q = 0; q < 4; ++q) {
      const int r = bm + i * 16 + rq0 + q;
      const float* gr = gum + (2 * r + g) * NV + wcol0 + frow;
#pragma unroll
      for (int j = 0; j < 5; ++j) gv[i][j][q] = gr[j * 16];
    }

  // per-row: max of raw logits; argmax of l+g (tie -> lowest col)
  float m[2][4], bv[2][4];
  int bi[2][4];
#pragma unroll
  for (int i = 0; i < 2; ++i)
#pragma unroll
    for (int q = 0; q < 4; ++q) {
      float mm = acc[i][0][q];
      float av = acc[i][0][q] + gv[i][0][q];
      int ai = wcol0 + frow;
#pragma unroll
      for (int j = 1; j < 5; ++j) {
        mm = fmaxf(mm, acc[i][j][q]);
        float a2 = acc[i][j][q] + gv[i][j][q];
        if (a2 > av) { av = a2; ai = wcol0 + j * 16 + frow; }
      }
#pragma unroll
      for (int o = 1; o < 16; o <<= 1) {
        mm = fmaxf(mm, __shfl_xor(mm, o));
        float ov = __shfl_xor(av, o);
        int oi = __shfl_xor(ai, o);
        if (ov > av || (ov == av && oi < ai)) { av = ov; ai = oi; }
      }
      m[i][q] = mm; bv[i][q] = av; bi[i][q] = ai;
    }
  if (frow == 0) {
#pragma unroll
    for (int i = 0; i < 2; ++i)
#pragma unroll
      for (int q = 0; q < 4; ++q) {
        const int row = i * 16 + rq0 + q;
        sm_m[w][row] = m[i][q];
        sm_av[w][row] = bv[i][q];
        sm_ai[w][row] = bi[i][q];
      }
  }
  __syncthreads();  // B1

  float gm[2][4];
#pragma unroll
  for (int i = 0; i < 2; ++i)
#pragma unroll
    for (int q = 0; q < 4; ++q) {
      const int row = i * 16 + rq0 + q;
      float mm = sm_m[0][row];
      float av = sm_av[0][row];
      int ai = sm_ai[0][row];
#pragma unroll
      for (int ww = 1; ww < 4; ++ww) {
        mm = fmaxf(mm, sm_m[ww][row]);
        float v2 = sm_av[ww][row];
        int i2 = sm_ai[ww][row];
        if (v2 > av || (v2 == av && i2 < ai)) { av = v2; ai = i2; }
      }
      gm[i][q] = mm;
      if (w == 0 && frow == 0) sm_idx[row] = ai;
    }

  // exp + row sum
  float rs[2][4];
#pragma unroll
  for (int i = 0; i < 2; ++i)
#pragma unroll
    for (int q = 0; q < 4; ++q) {
      float s = 0.f;
#pragma unroll
      for (int j = 0; j < 5; ++j) {
        float e = expf(acc[i][j][q] - gm[i][q]);
        acc[i][j][q] = e;
        s += e;
      }
#pragma unroll
      for (int o = 1; o < 16; o <<= 1) s += __shfl_xor(s, o);
      rs[i][q] = s;
    }
  if (frow == 0)
#pragma unroll
    for (int i = 0; i < 2; ++i)
#pragma unroll
      for (int q = 0; q < 4; ++q) sm_s[w][i * 16 + rq0 + q] = rs[i][q];
  __syncthreads();  // B2

  float rinv[2][4];
#pragma unroll
  for (int i = 0; i < 2; ++i)
#pragma unroll
    for (int q = 0; q < 4; ++q) {
      const int row = i * 16 + rq0 + q;
      rinv[i][q] = 1.f / ((sm_s[0][row] + sm_s[1][row]) + (sm_s[2][row] + sm_s[3][row]));
    }

  // marginal partials: col-sum of p over this block's 32 rows
#pragma unroll
  for (int j = 0; j < 5; ++j) {
    float p = 0.f;
#pragma unroll
    for (int i = 0; i < 2; ++i)
#pragma unroll
      for (int q = 0; q < 4; ++q) p += acc[i][j][q] * rinv[i][q];
    p += __shfl_xor(p, 16);
    p += __shfl_xor(p, 32);
    if (lane < 16) part[(g * 64 + mtile) * NV + wcol0 + j * 16 + lane] = p;
  }

  // fused gather: 32 rows x 128 floats, float4 per thread x4
#pragma unroll
  for (int it = 0; it < 4; ++it) {
    const int f4 = tid + it * 256;
    const int row = f4 >> 5;
    const int d = (f4 & 31) << 2;
    const int id = sm_idx[row];
    const float4 v = *(const float4*)(cvs + (g * NV + id) * DHALF + d);
    *(float4*)(out + (bm + row) * 256 + g * DHALF + d) = v;
  }
}

// ---------------- Reduce partials + perplexity: 40 blocks x 16 cols, 64 partials ----------
__global__ __launch_bounds__(256) void reduce_perp_kernel(
    const float* __restrict__ part, float* __restrict__ hpart,
    int* __restrict__ counter, float* __restrict__ perpOut) {
  const int t = threadIdx.x;
  const int rg = t >> 4, co = t & 15;
  const int col = blockIdx.x * 16 + co;  // 0..639; blocks 0..19 group0, 20..39 group1
  const int g = (col >= NV) ? 1 : 0;
  const int c = col - g * NV;
  float s = 0.f;
  for (int b = rg; b < 64; b += 16) s += part[(g * 64 + b) * NV + c];
  __shared__ float red[16][16];
  red[rg][co] = s;
  __syncthreads();
  if (t < 16) {
    float cs = 0.f;
#pragma unroll
    for (int j = 0; j < 16; ++j) cs += red[j][t];
    const float mm = cs * (1.0f / BSROWS);
    float h = mm * logf(mm + 1e-7f);
#pragma unroll
    for (int o = 8; o > 0; o >>= 1) h += __shfl_xor(h, o, 16);
    if (t == 0) {
      hpart[blockIdx.x] = h;
      __threadfence();
      const int old = atomicAdd(counter, 1);
      if (old == NRED - 1) {
        __threadfence();
        float h0 = 0.f, h1 = 0.f;
#pragma unroll
        for (int i = 0; i < 20; ++i) h0 += hpart[i];
#pragma unroll
        for (int i = 20; i < 40; ++i) h1 += hpart[i];
        perpOut[0] = expf(-h0) + expf(-h1);
      }
    }
  }
}

extern "C" void kernel_launch(void* const* d_in, const int* in_sizes, int n_in,
                              void* d_out, int out_size, void* d_ws, size_t ws_size,
                              hipStream_t stream) {
  const float* x = (const float*)d_in[0];
  const float* W = (const float*)d_in[1];
  const float* b = (const float*)d_in[2];
  const float* cvs = (const float*)d_in[3];
  const float* gum = (const float*)d_in[4];
  float* out = (float*)d_out;

  float* part = (float*)d_ws;            // 128*320 f32
  float* hpart = part + 128 * NV;        // 40 f32 (+pad)
  int* counter = (int*)(hpart + 64);     // 1 i32

  gemm_row_kernel<<<128, 256, 0, stream>>>(x, W, b, gum, cvs, out, part, counter);
  reduce_perp_kernel<<<NRED, 256, 0, stream>>>(part, hpart, counter, out + BSROWS * 256);
}